// Round 1
// baseline (248.588 us; speedup 1.0000x reference)
//
#include <hip/hip_runtime.h>

// Problem: EATransformerMHS_39779987096203
//   B=2, H=12, S=256, E=64, L=25, K=H*E=768
//   out[b,j,l,i] = sum_k p[b,k/64,i,j]*(v[b,k/64,j,k%64] + rel[b,i,j,k])*W[l,k] + bias[l]
//
// Strategy: memory-bound on rel (402.7 MB). One thread per (b,i,j) row; block
// owns one (b,j) with i = threadIdx. W transposed to Wt[768][32] in d_ws so
// per-k weights load via uniform (scalar) loads; v/bias also uniform-address
// scalar loads. rel read as float4 with 2-deep prefetch. No LDS.

#define Hh 12
#define Ss 256
#define Ee 64
#define Ll 25
#define Kk (Hh * Ee)      // 768
#define WT_STRIDE 32      // floats; 128B rows for aligned s_load

__global__ void wt_transpose_kernel(const float* __restrict__ W,
                                    float* __restrict__ Wt) {
    int idx = blockIdx.x * 256 + threadIdx.x;
    if (idx >= Kk * Ll) return;
    int k = idx / Ll, l = idx % Ll;
    Wt[k * WT_STRIDE + l] = W[l * Kk + k];
}

__global__ __launch_bounds__(256, 2) void mhs_main_kernel(
    const float* __restrict__ p,     // [B,H,S,S]
    const float* __restrict__ v,     // [B,H,S,E]
    const float* __restrict__ rel,   // [B,S,S,K]
    const float* __restrict__ Wt,    // [K,WT_STRIDE]
    const float* __restrict__ bias,  // [L]
    float* __restrict__ out)         // [B,S,L,S]
{
    const int j = blockIdx.x;
    const int b = blockIdx.y;
    const int i = threadIdx.x;

    const float* rel_row = rel + ((size_t)(b * Ss + i) * Ss + j) * Kk;
    const size_t p_base = (((size_t)b * Hh) * Ss + i) * Ss + j;  // + h*S*S
    const size_t v_base = (((size_t)b * Hh) * Ss + j) * Ee;      // + h*S*E + e

    float acc[Ll];
#pragma unroll
    for (int l = 0; l < Ll; ++l) acc[l] = 0.f;

    float phv = p[p_base];
    float4 A = *(const float4*)(rel_row + 0);
    float4 B4 = *(const float4*)(rel_row + 4);

    for (int h = 0; h < Hh; ++h) {
        const float ph_next = (h + 1 < Hh) ? p[p_base + (size_t)(h + 1) * Ss * Ss] : 0.f;
        const float* vrow = v + v_base + (size_t)h * Ss * Ee;
        const int kbase = h * Ee;
#pragma unroll 1
        for (int k0 = kbase; k0 < kbase + Ee; k0 += 8) {
            int kn = k0 + 8;
            if (kn >= Kk) kn = 0;  // tail guard: avoid reading past buffer end
            const float4 C = *(const float4*)(rel_row + kn);
            const float4 D = *(const float4*)(rel_row + kn + 4);

            const float* wr0 = Wt + (size_t)k0 * WT_STRIDE;
            const int e0 = k0 - kbase;
#pragma unroll
            for (int kk = 0; kk < 8; ++kk) {
                const float relv = (kk < 4) ? ((const float*)&A)[kk]
                                            : ((const float*)&B4)[kk - 4];
                const float s = phv * (vrow[e0 + kk] + relv);   // v: scalar load
                const float* wr = wr0 + kk * WT_STRIDE;         // uniform row
#pragma unroll
                for (int l = 0; l < Ll; ++l)
                    acc[l] = __builtin_fmaf(s, wr[l], acc[l]);  // s_load'd W
            }
            A = C; B4 = D;
        }
        phv = ph_next;
    }

    // out[b][j][l][i] = acc[l] + bias[l]; lanes along i -> coalesced stores
    float* orow = out + ((size_t)(b * Ss + j) * Ll) * Ss + i;
#pragma unroll
    for (int l = 0; l < Ll; ++l)
        orow[(size_t)l * Ss] = acc[l] + bias[l];
}

extern "C" void kernel_launch(void* const* d_in, const int* in_sizes, int n_in,
                              void* d_out, int out_size, void* d_ws, size_t ws_size,
                              hipStream_t stream) {
    const float* p    = (const float*)d_in[0];  // attention_probs [B,H,S,S]
    const float* v    = (const float*)d_in[1];  // value_attentions [B,H,S,E]
    const float* rel  = (const float*)d_in[2];  // relative_positions [B,S,S,H*E]
    const float* W    = (const float*)d_in[3];  // [L, H*E]
    const float* bias = (const float*)d_in[4];  // [L]
    float* out = (float*)d_out;
    float* Wt  = (float*)d_ws;                  // needs 768*32*4 = 98304 B

    const int B = in_sizes[0] / (Hh * Ss * Ss); // = 2

    hipLaunchKernelGGL(wt_transpose_kernel, dim3((Kk * Ll + 255) / 256), dim3(256),
                       0, stream, W, Wt);
    hipLaunchKernelGGL(mhs_main_kernel, dim3(Ss, B), dim3(256),
                       0, stream, p, v, rel, Wt, bias, out);
}

// Round 2
// 212.190 us; speedup vs baseline: 1.1715x; 1.1715x over previous
//
#include <hip/hip_runtime.h>
#include <stdint.h>

// Problem: EATransformerMHS_39779987096203
//   B=2, H=12, S=256, E=64, L=25, K=H*E=768
//   out[b,j,l,i] = sum_k p[b,k/64,i,j]*(v[b,k/64,j,k%64] + rel[b,i,j,k])*W[l,k] + bias[l]
//
// Structure: 1-wave blocks, lanes <-> i (64 rows), k swept sequentially so
// W (Wt[k][32]) and v stay wave-uniform scalar loads. rel staged to LDS in
// 32-k chunks via global_load_lds (16B), double-buffered, with XOR source
// swizzle so the ds_read_b128 per-row reads are ~conflict-free.
// p pre-transposed to p_t[b][j][h][i] so per-chunk p loads coalesce.

#define Bb 2
#define Hh 12
#define Ss 256
#define Ee 64
#define Ll 25
#define Kk 768
#define CHUNK 32
#define NCHUNK (Kk / CHUNK)   // 24
#define WT_STRIDE 32

#define PT_ELEMS (Bb * Ss * Hh * Ss)       // p_t[b][j][h][i]
#define PT_BYTES ((size_t)PT_ELEMS * 4)    // 6,291,456
#define WT_BYTES ((size_t)Kk * WT_STRIDE * 4)  // 98,304

typedef const void __attribute__((address_space(1)))* gas_ptr;
typedef void __attribute__((address_space(3)))* las_ptr;

__device__ __forceinline__ void async_copy16(void* lds_dst, const void* g_src) {
    __builtin_amdgcn_global_load_lds((gas_ptr)g_src, (las_ptr)lds_dst, 16, 0, 0);
}

__global__ void wt_transpose_kernel(const float* __restrict__ W,
                                    float* __restrict__ Wt) {
    int idx = blockIdx.x * 256 + threadIdx.x;
    if (idx >= Kk * Ll) return;
    int k = idx / Ll, l = idx % Ll;
    Wt[k * WT_STRIDE + l] = W[l * Kk + k];
}

// p[b][h][i][j] -> p_t[b][j][h][i], tiled 32x32 transpose per (b,h)
__global__ void p_transpose_kernel(const float* __restrict__ p,
                                   float* __restrict__ pt) {
    __shared__ float tile[32][33];
    const int bh = blockIdx.y;            // 0..23
    const int b = bh / Hh, h = bh % Hh;
    const int ti = blockIdx.x >> 3, tj = blockIdx.x & 7;  // 8x8 tiles of 32
    const int tx = threadIdx.x & 31, ty = threadIdx.x >> 5;  // 32x8
#pragma unroll
    for (int s = 0; s < 4; ++s) {
        const int il = ty + 8 * s;
        tile[il][tx] = p[((size_t)(b * Hh + h) * Ss + ti * 32 + il) * Ss + tj * 32 + tx];
    }
    __syncthreads();
#pragma unroll
    for (int s = 0; s < 4; ++s) {
        const int jl = ty + 8 * s;
        pt[((size_t)(b * Ss + tj * 32 + jl) * Hh + h) * Ss + ti * 32 + tx] = tile[tx][jl];
    }
}

template <bool FULL>
__global__ __launch_bounds__(64, 2) void mhs_main(
    const float* __restrict__ p,    // [B,H,S,S]   (used when !FULL)
    const float* __restrict__ pt,   // [B,S,H,S]   (FULL)
    const float* __restrict__ v,    // [B,H,S,E]
    const float* __restrict__ rel,  // [B,S,S,K]
    const float* __restrict__ W,    // [L,K]       (!FULL)
    const float* __restrict__ wt,   // [K,32]      (FULL)
    const float* __restrict__ bias, // [L]
    float* __restrict__ out)        // [B,S,L,S]
{
    __shared__ __align__(16) float lds[2][CHUNK * 64];  // 2 x 8 KB

    const int g = blockIdx.x;          // [b][j][ig]
    const int ig = g & 3;
    const int j = (g >> 2) & (Ss - 1);
    const int b = g >> 10;
    const int lane = threadIdx.x;      // 0..63, row = i0 + lane
    const int i0 = ig * 64;

    const size_t rel0 = ((size_t)(b * Ss + i0) * Ss + j) * Kk;
    const int q = lane >> 3;               // row-within-octet selector
    const int grp = (lane & 7) ^ q;        // XOR source swizzle (t-independent)

    // STAGE chunk cc into lds[dstbuf]: 8 x global_load_lds dwordx4
#define STAGE(dstbuf, cc)                                                        \
    do {                                                                         \
        const size_t koff = (size_t)(cc) * CHUNK;                                \
        _Pragma("unroll")                                                        \
        for (int t = 0; t < 8; ++t) {                                            \
            const int r = t * 8 + q;                                             \
            const float* src = rel + rel0 + (size_t)r * (Ss * Kk) + koff + grp * 4; \
            async_copy16(&lds[dstbuf][t * 256], src);                            \
        }                                                                        \
    } while (0)

    float acc[Ll];
#pragma unroll
    for (int l = 0; l < Ll; ++l) acc[l] = 0.f;

    STAGE(0, 0);
    __syncthreads();  // drains vmcnt -> chunk 0 ready

    // per-(h,lane) attention prob
    auto load_p = [&](int h) -> float {
        if (FULL)
            return pt[((size_t)(b * Ss + j) * Hh + h) * Ss + i0 + lane];
        else
            return p[((size_t)(b * Hh + h) * Ss + i0 + lane) * Ss + j];
    };

    float ph = load_p(0);
    int buf = 0;

    for (int c = 0; c < NCHUNK; ++c) {
        if (c + 1 < NCHUNK) STAGE(buf ^ 1, c + 1);
        const float ph_next = (c + 1 < NCHUNK) ? load_p((c + 1) >> 1) : 0.f;

        const int h = c >> 1;
        const float* vrow = v + ((size_t)(b * Hh + h) * Ss + j) * Ee + (c & 1) * CHUNK;

#pragma unroll
        for (int kg = 0; kg < 8; ++kg) {
            const int slot = kg ^ (lane & 7);
            const float4 rv = *(const float4*)&lds[buf][lane * 32 + slot * 4];
#pragma unroll
            for (int kk = 0; kk < 4; ++kk) {
                const int klocal = kg * 4 + kk;
                const float relv = ((const float*)&rv)[kk];
                const float s = ph * (vrow[klocal] + relv);
                if (FULL) {
                    const float* wr = wt + (size_t)(c * CHUNK + klocal) * WT_STRIDE;
#pragma unroll
                    for (int l = 0; l < Ll; ++l)
                        acc[l] = __builtin_fmaf(s, wr[l], acc[l]);
                } else {
                    const int kglob = c * CHUNK + klocal;
#pragma unroll
                    for (int l = 0; l < Ll; ++l)
                        acc[l] = __builtin_fmaf(s, W[l * Kk + kglob], acc[l]);
                }
            }
        }
        __syncthreads();  // safe to overwrite buf next iter; drains prefetch
        buf ^= 1;
        ph = ph_next;
    }
#undef STAGE

    float* orow = out + ((size_t)(b * Ss + j) * Ll) * Ss + i0 + lane;
#pragma unroll
    for (int l = 0; l < Ll; ++l)
        orow[(size_t)l * Ss] = acc[l] + bias[l];
}

extern "C" void kernel_launch(void* const* d_in, const int* in_sizes, int n_in,
                              void* d_out, int out_size, void* d_ws, size_t ws_size,
                              hipStream_t stream) {
    const float* p    = (const float*)d_in[0];
    const float* v    = (const float*)d_in[1];
    const float* rel  = (const float*)d_in[2];
    const float* W    = (const float*)d_in[3];
    const float* bias = (const float*)d_in[4];
    float* out = (float*)d_out;

    const bool full = ws_size >= PT_BYTES + WT_BYTES;
    const int nblk = Bb * Ss * 4;  // 2048

    if (full) {
        float* pt = (float*)d_ws;
        float* wt = (float*)((char*)d_ws + PT_BYTES);
        hipLaunchKernelGGL(p_transpose_kernel, dim3(64, Bb * Hh), dim3(256), 0, stream,
                           p, pt);
        hipLaunchKernelGGL(wt_transpose_kernel, dim3((Kk * Ll + 255) / 256), dim3(256),
                           0, stream, W, wt);
        hipLaunchKernelGGL((mhs_main<true>), dim3(nblk), dim3(64), 0, stream,
                           p, pt, v, rel, W, wt, bias, out);
    } else {
        hipLaunchKernelGGL((mhs_main<false>), dim3(nblk), dim3(64), 0, stream,
                           p, (const float*)nullptr, v, rel, W, (const float*)nullptr,
                           bias, out);
    }
}

// Round 3
// 146.326 us; speedup vs baseline: 1.6989x; 1.4501x over previous
//
#include <hip/hip_runtime.h>
#include <stdint.h>

// EATransformerMHS: B=2,H=12,S=256,E=64,L=25,K=768
// out[b,j,l,i] = sum_k p[b,k/64,i,j]*(v[b,k/64,j,k%64] + rel[b,i,j,k])*W[l,k] + b[l]
//
// MFMA restructure: per (b,j,h):  C_h[LxI] = W_h[Lx64] . (v_h + rel_h)[Ix64]^T
// via mfma_f32_16x16x32_bf16 (2 k-steps), then acc[l,i] += p[h,i]*C_h[l,i] on VALU.
// B-fragments (8 consecutive k per lane, col=lane&15) load STRAIGHT from rel as
// 2x float4 per lane -> no LDS, no scalar-load stalls, no barriers.
// A-fragments pre-packed to bf16 in d_ws (48KB, L padded 25->32 with zeros);
// A and B packed with the same k-slot convention -> result invariant to the
// HW's internal k-permutation. C layout (m89-verified): col=lane&15,
// row=(lane>>4)*4+r.

#define Bb 2
#define Hh 12
#define Ss 256
#define Ee 64
#define Ll 25
#define Kk 768

typedef __attribute__((ext_vector_type(8))) short bf16x8;
typedef __attribute__((ext_vector_type(4))) float f32x4;

#define NFRAG (Hh * 4)                          // (h, ks, Lt)
#define AB_BYTES ((size_t)NFRAG * 64 * 8 * 2)   // 49152
#define PT_BYTES ((size_t)Bb * Ss * Hh * Ss * 4)

__device__ __forceinline__ ushort f2bf(float x) {  // RNE f32->bf16
    union { float f; uint32_t u; } v; v.f = x;
    uint32_t r = v.u + 0x7fff + ((v.u >> 16) & 1);
    return (ushort)(r >> 16);
}

// Pack W[L,K] (f32) into per-lane A-fragments: frag fi=h*4+ks*2+Lt,
// lane holds A[l=Lt*16+(lane&15), k=h*64+ks*32+(lane>>4)*8+t], t=0..7.
__global__ void a_pack_kernel(const float* __restrict__ W, ushort* __restrict__ ab) {
    int idx = blockIdx.x * 256 + threadIdx.x;
    if (idx >= NFRAG * 64) return;
    int lane = idx & 63, fi = idx >> 6;
    int Lt = fi & 1, ks = (fi >> 1) & 1, h = fi >> 2;
    int l = Lt * 16 + (lane & 15);
    int k0 = h * Ee + ks * 32 + (lane >> 4) * 8;
    ushort* dst = ab + (size_t)idx * 8;
#pragma unroll
    for (int t = 0; t < 8; ++t)
        dst[t] = (l < Ll) ? f2bf(W[l * Kk + k0 + t]) : (ushort)0;
}

// p[b][h][i][j] -> pt[b][j][h][i]
__global__ void p_transpose_kernel(const float* __restrict__ p,
                                   float* __restrict__ pt) {
    __shared__ float tile[32][33];
    const int bh = blockIdx.y;
    const int b = bh / Hh, h = bh % Hh;
    const int ti = blockIdx.x >> 3, tj = blockIdx.x & 7;
    const int tx = threadIdx.x & 31, ty = threadIdx.x >> 5;
#pragma unroll
    for (int s = 0; s < 4; ++s) {
        const int il = ty + 8 * s;
        tile[il][tx] = p[((size_t)(b * Hh + h) * Ss + ti * 32 + il) * Ss + tj * 32 + tx];
    }
    __syncthreads();
#pragma unroll
    for (int s = 0; s < 4; ++s) {
        const int jl = ty + 8 * s;
        pt[((size_t)(b * Ss + tj * 32 + jl) * Hh + h) * Ss + ti * 32 + tx] = tile[tx][jl];
    }
}

template <bool FULL>
__global__ __launch_bounds__(64) void mhs_mfma(
    const float* __restrict__ p,    // [B,H,S,S] (!FULL)
    const float* __restrict__ pt,   // [B,S,H,S] (FULL)
    const float* __restrict__ v,    // [B,H,S,E]
    const float* __restrict__ rel,  // [B,S,S,K]
    const float* __restrict__ W,    // [L,K]     (!FULL)
    const ushort* __restrict__ ab,  // packed A frags (FULL)
    const float* __restrict__ bias, // [L]
    float* __restrict__ out)        // [B,S,L,S]
{
    const int g = blockIdx.x;                 // [b][j][ig]
    const int ig = g & 3, j = (g >> 2) & (Ss - 1), b = g >> 10;
    const int lane = threadIdx.x & 63;
    const int col = lane & 15, grp = lane >> 4;
    const int i0 = ig * 64;

    f32x4 acc[2][4];
#pragma unroll
    for (int Lt = 0; Lt < 2; ++Lt)
#pragma unroll
        for (int it = 0; it < 4; ++it)
            acc[Lt][it] = (f32x4){0.f, 0.f, 0.f, 0.f};

    const float* relb[4];
#pragma unroll
    for (int it = 0; it < 4; ++it)
        relb[it] = rel + ((size_t)(b * Ss + i0 + it * 16 + col) * Ss + j) * Kk + grp * 8;

#pragma unroll 1
    for (int h = 0; h < Hh; ++h) {
        // A fragments (L2-hot 48KB buffer, 1KB coalesced per frag per wave)
        bf16x8 A00, A01, A10, A11;  // A[ks][Lt]
        if (FULL) {
            const ushort* abase = ab + (size_t)(h * 4) * 512 + lane * 8;
            A00 = *(const bf16x8*)(abase);
            A01 = *(const bf16x8*)(abase + 512);
            A10 = *(const bf16x8*)(abase + 1024);
            A11 = *(const bf16x8*)(abase + 1536);
        } else {
#pragma unroll
            for (int t = 0; t < 8; ++t) {
                const int kb = h * Ee + grp * 8 + t;
                const int la = col, lb = 16 + col;
                A00[t] = (short)f2bf(W[la * Kk + kb]);
                A01[t] = (lb < Ll) ? (short)f2bf(W[lb * Kk + kb]) : (short)0;
                A10[t] = (short)f2bf(W[la * Kk + kb + 32]);
                A11[t] = (lb < Ll) ? (short)f2bf(W[lb * Kk + kb + 32]) : (short)0;
            }
        }

        // v slice for this (b,h,j): e = ks*32 + grp*8 + t (broadcast in 16-lane groups)
        const float* vbp = v + ((size_t)(b * Hh + h) * Ss + j) * Ee + grp * 8;
        const float4 va0 = *(const float4*)(vbp);
        const float4 va1 = *(const float4*)(vbp + 4);
        const float4 vc0 = *(const float4*)(vbp + 32);
        const float4 vc1 = *(const float4*)(vbp + 36);

        float pv[4];
#pragma unroll
        for (int it = 0; it < 4; ++it) {
            if (FULL)
                pv[it] = pt[((size_t)(b * Ss + j) * Hh + h) * Ss + i0 + it * 16 + col];
            else
                pv[it] = p[((size_t)(b * Hh + h) * Ss + i0 + it * 16 + col) * Ss + j];
        }

#pragma unroll
        for (int it = 0; it < 4; ++it) {
            const float* rb = relb[it] + h * Ee;
            const float4 x0 = *(const float4*)(rb);       // ks=0, t=0..3
            const float4 x1 = *(const float4*)(rb + 4);   // ks=0, t=4..7
            const float4 y0 = *(const float4*)(rb + 32);  // ks=1
            const float4 y1 = *(const float4*)(rb + 36);
            bf16x8 B0, B1;
#pragma unroll
            for (int t = 0; t < 4; ++t) {
                B0[t]     = (short)f2bf(((const float*)&x0)[t] + ((const float*)&va0)[t]);
                B0[t + 4] = (short)f2bf(((const float*)&x1)[t] + ((const float*)&va1)[t]);
                B1[t]     = (short)f2bf(((const float*)&y0)[t] + ((const float*)&vc0)[t]);
                B1[t + 4] = (short)f2bf(((const float*)&y1)[t] + ((const float*)&vc1)[t]);
            }
            f32x4 C0 = {0.f, 0.f, 0.f, 0.f}, C1 = {0.f, 0.f, 0.f, 0.f};
            C0 = __builtin_amdgcn_mfma_f32_16x16x32_bf16(A00, B0, C0, 0, 0, 0);
            C0 = __builtin_amdgcn_mfma_f32_16x16x32_bf16(A10, B1, C0, 0, 0, 0);
            C1 = __builtin_amdgcn_mfma_f32_16x16x32_bf16(A01, B0, C1, 0, 0, 0);
            C1 = __builtin_amdgcn_mfma_f32_16x16x32_bf16(A11, B1, C1, 0, 0, 0);
            acc[0][it] += pv[it] * C0;
            acc[1][it] += pv[it] * C1;
        }
    }

    // C/D layout: col=lane&15 (=i_local), row=(lane>>4)*4+r (=l within 16-tile)
#pragma unroll
    for (int Lt = 0; Lt < 2; ++Lt)
#pragma unroll
        for (int r = 0; r < 4; ++r) {
            const int l = Lt * 16 + grp * 4 + r;
            if (l < Ll) {
                const float bv = bias[l];
#pragma unroll
                for (int it = 0; it < 4; ++it)
                    out[((size_t)(b * Ss + j) * Ll + l) * Ss + i0 + it * 16 + col] =
                        acc[Lt][it][r] + bv;
            }
        }
}

extern "C" void kernel_launch(void* const* d_in, const int* in_sizes, int n_in,
                              void* d_out, int out_size, void* d_ws, size_t ws_size,
                              hipStream_t stream) {
    const float* p    = (const float*)d_in[0];
    const float* v    = (const float*)d_in[1];
    const float* rel  = (const float*)d_in[2];
    const float* W    = (const float*)d_in[3];
    const float* bias = (const float*)d_in[4];
    float* out = (float*)d_out;

    const int nblk = Bb * Ss * 4;  // 2048 one-wave blocks
    const bool full = ws_size >= AB_BYTES + PT_BYTES;

    if (full) {
        ushort* ab = (ushort*)d_ws;
        float* pt = (float*)((char*)d_ws + AB_BYTES);
        hipLaunchKernelGGL(a_pack_kernel, dim3((NFRAG * 64 + 255) / 256), dim3(256),
                           0, stream, W, ab);
        hipLaunchKernelGGL(p_transpose_kernel, dim3(64, Bb * Hh), dim3(256),
                           0, stream, p, pt);
        hipLaunchKernelGGL((mhs_mfma<true>), dim3(nblk), dim3(64), 0, stream,
                           p, pt, v, rel, W, ab, bias, out);
    } else {
        hipLaunchKernelGGL((mhs_mfma<false>), dim3(nblk), dim3(64), 0, stream,
                           p, (const float*)nullptr, v, rel, W,
                           (const ushort*)nullptr, bias, out);
    }
}

// Round 4
// 112.448 us; speedup vs baseline: 2.2107x; 1.3013x over previous
//
#include <hip/hip_runtime.h>
#include <stdint.h>

// EATransformerMHS: B=2,H=12,S=256,E=64,L=25,K=768
// out[b,j,l,i] = sum_k p[b,k/64,i,j]*(v[b,k/64,j,k%64] + rel[b,i,j,k])*W[l,k] + b[l]
//
// MFMA restructure: per (b,j,h):  C_h[LxI] = W_h[Lx64] . (v_h + rel_h)[Ix64]^T
// via mfma_f32_16x16x32_bf16, then acc[l,i] += p[h,i]*C_h[l,i] on the VALU.
// rel feeds the MFMA B-operand straight from per-lane float4 global loads.
//
// Round-3 change (latency -> BW bound): 256-thread blocks, each of the 4
// waves owns ONE 16-row i-tile (8192 waves total, ~16/CU), and rel is
// software-pipelined one h ahead (4KB/wave in flight). No LDS, no barriers.

#define Bb 2
#define Hh 12
#define Ss 256
#define Ee 64
#define Ll 25
#define Kk 768

typedef __attribute__((ext_vector_type(8))) short bf16x8;
typedef __attribute__((ext_vector_type(4))) float f32x4;

#define NFRAG (Hh * 4)                          // (h, ks, Lt)
#define AB_BYTES ((size_t)NFRAG * 64 * 8 * 2)   // 49152
#define PT_BYTES ((size_t)Bb * Ss * Hh * Ss * 4)

__device__ __forceinline__ ushort f2bf(float x) {  // RNE f32->bf16
    union { float f; uint32_t u; } u; u.f = x;
    uint32_t r = u.u + 0x7fff + ((u.u >> 16) & 1);
    return (ushort)(r >> 16);
}

// Pack W[L,K] into per-lane A-fragments: frag fi=h*4+ks*2+Lt,
// lane holds A[l=Lt*16+(lane&15), k=h*64+ks*32+(lane>>4)*8+t], t=0..7.
__global__ void a_pack_kernel(const float* __restrict__ W, ushort* __restrict__ ab) {
    int idx = blockIdx.x * 256 + threadIdx.x;
    if (idx >= NFRAG * 64) return;
    int lane = idx & 63, fi = idx >> 6;
    int Lt = fi & 1, ks = (fi >> 1) & 1, h = fi >> 2;
    int l = Lt * 16 + (lane & 15);
    int k0 = h * Ee + ks * 32 + (lane >> 4) * 8;
    ushort* dst = ab + (size_t)idx * 8;
#pragma unroll
    for (int t = 0; t < 8; ++t)
        dst[t] = (l < Ll) ? f2bf(W[l * Kk + k0 + t]) : (ushort)0;
}

// p[b][h][i][j] -> pt[b][j][h][i]
__global__ void p_transpose_kernel(const float* __restrict__ p,
                                   float* __restrict__ pt) {
    __shared__ float tile[32][33];
    const int bh = blockIdx.y;
    const int b = bh / Hh, h = bh % Hh;
    const int ti = blockIdx.x >> 3, tj = blockIdx.x & 7;
    const int tx = threadIdx.x & 31, ty = threadIdx.x >> 5;
#pragma unroll
    for (int s = 0; s < 4; ++s) {
        const int il = ty + 8 * s;
        tile[il][tx] = p[((size_t)(b * Hh + h) * Ss + ti * 32 + il) * Ss + tj * 32 + tx];
    }
    __syncthreads();
#pragma unroll
    for (int s = 0; s < 4; ++s) {
        const int jl = ty + 8 * s;
        pt[((size_t)(b * Ss + tj * 32 + jl) * Hh + h) * Ss + ti * 32 + tx] = tile[tx][jl];
    }
}

template <bool FULL>
__global__ __launch_bounds__(256, 4) void mhs_mfma(
    const float* __restrict__ p,    // [B,H,S,S] (!FULL)
    const float* __restrict__ pt,   // [B,S,H,S] (FULL)
    const float* __restrict__ v,    // [B,H,S,E]
    const float* __restrict__ rel,  // [B,S,S,K]
    const float* __restrict__ W,    // [L,K]     (!FULL)
    const ushort* __restrict__ ab,  // packed A frags (FULL)
    const float* __restrict__ bias, // [L]
    float* __restrict__ out)        // [B,S,L,S]
{
    const int g = blockIdx.x;                 // [b][j][ig]
    const int ig = g & 3, j = (g >> 2) & (Ss - 1), b = g >> 10;
    const int tid = threadIdx.x;
    const int w = tid >> 6, lane = tid & 63;
    const int col = lane & 15, grp = lane >> 4;
    const int iw = ig * 64 + w * 16 + col;    // this lane's output row i

    const float* relp = rel + ((size_t)(b * Ss + iw) * Ss + j) * Kk + grp * 8;

    f32x4 acc0 = {0.f, 0.f, 0.f, 0.f};
    f32x4 acc1 = {0.f, 0.f, 0.f, 0.f};

    // prime the rel pipeline (h=0)
    float4 c0 = *(const float4*)(relp);
    float4 c1 = *(const float4*)(relp + 4);
    float4 c2 = *(const float4*)(relp + 32);
    float4 c3 = *(const float4*)(relp + 36);

#pragma unroll 1
    for (int h = 0; h < Hh; ++h) {
        // issue next h's rel loads first (clamped on last iter -> L1 hit)
        const int hn = (h + 1 < Hh) ? h + 1 : h;
        const float* rn = relp + hn * Ee;
        const float4 n0 = *(const float4*)(rn);
        const float4 n1 = *(const float4*)(rn + 4);
        const float4 n2 = *(const float4*)(rn + 32);
        const float4 n3 = *(const float4*)(rn + 36);

        // A fragments (48KB L2-hot)
        bf16x8 A00, A01, A10, A11;  // [ks][Lt]
        if (FULL) {
            const ushort* abase = ab + (size_t)(h * 4) * 512 + lane * 8;
            A00 = *(const bf16x8*)(abase);
            A01 = *(const bf16x8*)(abase + 512);
            A10 = *(const bf16x8*)(abase + 1024);
            A11 = *(const bf16x8*)(abase + 1536);
        } else {
#pragma unroll
            for (int t = 0; t < 8; ++t) {
                const int kb = h * Ee + grp * 8 + t;
                const int la = col, lb = 16 + col;
                A00[t] = (short)f2bf(W[la * Kk + kb]);
                A01[t] = (lb < Ll) ? (short)f2bf(W[lb * Kk + kb]) : (short)0;
                A10[t] = (short)f2bf(W[la * Kk + kb + 32]);
                A11[t] = (lb < Ll) ? (short)f2bf(W[lb * Kk + kb + 32]) : (short)0;
            }
        }

        // v slice (broadcast within 16-lane groups; L2-hot)
        const float* vbp = v + ((size_t)(b * Hh + h) * Ss + j) * Ee + grp * 8;
        const float4 va0 = *(const float4*)(vbp);
        const float4 va1 = *(const float4*)(vbp + 4);
        const float4 vc0 = *(const float4*)(vbp + 32);
        const float4 vc1 = *(const float4*)(vbp + 36);

        const float pv = FULL
            ? pt[((size_t)(b * Ss + j) * Hh + h) * Ss + iw]
            : p[((size_t)(b * Hh + h) * Ss + iw) * Ss + j];

        bf16x8 B0, B1;
#pragma unroll
        for (int t = 0; t < 4; ++t) {
            B0[t]     = (short)f2bf(((const float*)&c0)[t] + ((const float*)&va0)[t]);
            B0[t + 4] = (short)f2bf(((const float*)&c1)[t] + ((const float*)&va1)[t]);
            B1[t]     = (short)f2bf(((const float*)&c2)[t] + ((const float*)&vc0)[t]);
            B1[t + 4] = (short)f2bf(((const float*)&c3)[t] + ((const float*)&vc1)[t]);
        }
        f32x4 C0 = {0.f, 0.f, 0.f, 0.f}, C1 = {0.f, 0.f, 0.f, 0.f};
        C0 = __builtin_amdgcn_mfma_f32_16x16x32_bf16(A00, B0, C0, 0, 0, 0);
        C0 = __builtin_amdgcn_mfma_f32_16x16x32_bf16(A10, B1, C0, 0, 0, 0);
        C1 = __builtin_amdgcn_mfma_f32_16x16x32_bf16(A01, B0, C1, 0, 0, 0);
        C1 = __builtin_amdgcn_mfma_f32_16x16x32_bf16(A11, B1, C1, 0, 0, 0);
        acc0 += pv * C0;
        acc1 += pv * C1;

        c0 = n0; c1 = n1; c2 = n2; c3 = n3;
    }

    // C/D layout: col=lane&15 (=i_local), row=(lane>>4)*4+r (=l within 16-tile)
#pragma unroll
    for (int r = 0; r < 4; ++r) {
        const int l0 = grp * 4 + r;
        out[((size_t)(b * Ss + j) * Ll + l0) * Ss + iw] = acc0[r] + bias[l0];
        const int l1 = 16 + grp * 4 + r;
        if (l1 < Ll)
            out[((size_t)(b * Ss + j) * Ll + l1) * Ss + iw] = acc1[r] + bias[l1];
    }
}

extern "C" void kernel_launch(void* const* d_in, const int* in_sizes, int n_in,
                              void* d_out, int out_size, void* d_ws, size_t ws_size,
                              hipStream_t stream) {
    const float* p    = (const float*)d_in[0];
    const float* v    = (const float*)d_in[1];
    const float* rel  = (const float*)d_in[2];
    const float* W    = (const float*)d_in[3];
    const float* bias = (const float*)d_in[4];
    float* out = (float*)d_out;

    const int nblk = Bb * Ss * 4;  // 2048 blocks x 256 threads
    const bool full = ws_size >= AB_BYTES + PT_BYTES;

    if (full) {
        ushort* ab = (ushort*)d_ws;
        float* pt = (float*)((char*)d_ws + AB_BYTES);
        hipLaunchKernelGGL(a_pack_kernel, dim3((NFRAG * 64 + 255) / 256), dim3(256),
                           0, stream, W, ab);
        hipLaunchKernelGGL(p_transpose_kernel, dim3(64, Bb * Hh), dim3(256),
                           0, stream, p, pt);
        hipLaunchKernelGGL((mhs_mfma<true>), dim3(nblk), dim3(256), 0, stream,
                           p, pt, v, rel, W, ab, bias, out);
    } else {
        hipLaunchKernelGGL((mhs_mfma<false>), dim3(nblk), dim3(256), 0, stream,
                           p, (const float*)nullptr, v, rel, W,
                           (const ushort*)nullptr, bias, out);
    }
}